// Round 2
// baseline (360.261 us; speedup 1.0000x reference)
//
#include <hip/hip_runtime.h>
#include <math.h>

#define RAD 20
#define KLEN 41
#define NH 1024
#define NW 2048
#define NHW (NH * NW)

// One-time weight computation (1 block, 64 threads). Matches numpy's fp64
// path: phi = exp(-0.5/25 * d^2); phi /= sum(phi); k = -d/25 * phi; cast f32.
// The 1/2.27 derivative scale (D_AP == D_DV) is folded in.
__global__ __launch_bounds__(64) void k_weights(float* __restrict__ kw_g) {
  const int t = threadIdx.x;
  const double d = (double)(t - RAD);
  const double ph = (t < KLEN) ? exp((-0.5 / 25.0) * d * d) : 0.0;
  double s = ph;
#pragma unroll
  for (int off = 1; off < 64; off <<= 1) s += __shfl_xor(s, off, 64);
  if (t < KLEN) {
    float w = (float)((-d / 25.0) * (ph / s));
    kw_g[t] = w * (float)(1.0 / 2.27);
  }
}

__device__ __forceinline__ void load_weights(const float* __restrict__ kw_g,
                                             float* kw) {
  if (threadIdx.x < KLEN) kw[threadIdx.x] = kw_g[threadIdx.x];
  __syncthreads();
}

// m_0 numerator: sum over pixels of ||m||_F (fp32 sqrt, fp64 accumulate).
__global__ __launch_bounds__(256) void k_reduce(const float* __restrict__ y,
                                                double* __restrict__ acc) {
  const int tid = blockIdx.x * blockDim.x + threadIdx.x;
  const int stride = gridDim.x * blockDim.x;
  double local = 0.0;
  for (int i = tid; i < NHW; i += stride) {
    float a = y[i];
    float b = y[i + NHW];
    float c = y[i + 2 * (size_t)NHW];
    float d = y[i + 3 * (size_t)NHW];
    local += (double)sqrtf(a * a + b * b + c * c + d * d);
  }
#pragma unroll
  for (int off = 32; off > 0; off >>= 1) local += __shfl_down(local, off, 64);
  __shared__ double smem[4];
  const int lane = threadIdx.x & 63;
  const int wid = threadIdx.x >> 6;
  if (lane == 0) smem[wid] = local;
  __syncthreads();
  if (threadIdx.x == 0) {
    double s = smem[0] + smem[1] + smem[2] + smem[3];
    atomicAdd(acc, s);
  }
}

// diffX: reflect pad along W, one block = one full row of one channel.
// 256 threads x 8 px/thread = 2048 = NW. Window = 48 floats in registers.
__global__ __launch_bounds__(256) void k_dx(const float* __restrict__ y,
                                            const float* __restrict__ v,
                                            const float* __restrict__ kw_g,
                                            float* __restrict__ ws) {
  __shared__ float kw[KLEN];
  load_weights(kw_g, kw);
  const int t = threadIdx.x;
  const int row = blockIdx.x;
  const int ch = blockIdx.y;  // 0..6 -> y0..y4, v0, v1
  const float* src = (ch < 5) ? (y + (size_t)ch * NHW) : (v + (size_t)(ch - 5) * NHW);
  const float* rp = src + (size_t)row * NW;
  float win[48];
  const int x0 = t * 8 - RAD;  // x0 % 4 == 0 -> float4-aligned when interior
  if (x0 >= 0 && x0 + 48 <= NW) {
#pragma unroll
    for (int i = 0; i < 12; ++i) {
      float4 f = *(const float4*)(rp + x0 + 4 * i);
      win[4 * i + 0] = f.x;
      win[4 * i + 1] = f.y;
      win[4 * i + 2] = f.z;
      win[4 * i + 3] = f.w;
    }
  } else {
#pragma unroll
    for (int i = 0; i < 48; ++i) {
      int xi = x0 + i;
      if (xi < 0) xi = -xi;                  // numpy 'reflect' (no edge repeat)
      if (xi >= NW) xi = 2 * NW - 2 - xi;
      win[i] = rp[xi];
    }
  }
  float res[8];
#pragma unroll
  for (int p = 0; p < 8; ++p) {
    float a = 0.f;
#pragma unroll
    for (int j = 0; j < KLEN; ++j) a = fmaf(win[p + j], kw[j], a);
    res[p] = a;
  }
  float* dst = ws + (size_t)(7 + ch) * NHW + (size_t)row * NW + t * 8;
#pragma unroll
  for (int p = 0; p < 8; ++p) dst[p] = res[p];
}

// diffY: wrap pad along H. Lanes contiguous in x (coalesced row reads),
// each thread produces 8 consecutive rows at its x.
__global__ __launch_bounds__(256) void k_dy(const float* __restrict__ y,
                                            const float* __restrict__ v,
                                            const float* __restrict__ kw_g,
                                            float* __restrict__ ws) {
  __shared__ float kw[KLEN];
  load_weights(kw_g, kw);
  const int x = blockIdx.x * 256 + threadIdx.x;
  const int y0 = blockIdx.y * 8;
  const int ch = blockIdx.z;
  const float* src = (ch < 5) ? (y + (size_t)ch * NHW) : (v + (size_t)(ch - 5) * NHW);
  float win[48];
#pragma unroll
  for (int i = 0; i < 48; ++i) {
    int yi = y0 - RAD + i;
    if (yi < 0) yi += NH;     // wrap
    if (yi >= NH) yi -= NH;
    win[i] = src[(size_t)yi * NW + x];
  }
  float* dst = ws + (size_t)ch * NHW + (size_t)y0 * NW + x;
#pragma unroll
  for (int p = 0; p < 8; ++p) {
    float a = 0.f;
#pragma unroll
    for (int j = 0; j < KLEN; ++j) a = fmaf(win[p + j], kw[j], a);
    dst[(size_t)p * NW] = a;
  }
}

// Pointwise 2x2 tensor algebra. ws planes: [0..6]=dY(ch), [7..13]=dX(ch).
__global__ __launch_bounds__(256) void k_final(
    const float* __restrict__ y, const float* __restrict__ v,
    const float* __restrict__ gds, const float* __restrict__ cadc,
    const float* __restrict__ myoc, const float* __restrict__ ws,
    const double* __restrict__ acc, float* __restrict__ out) {
  const size_t i = (size_t)blockIdx.x * blockDim.x + threadIdx.x;
  if (i >= NHW) return;

  const float m0 = (float)(acc[0] / (double)NHW);
  const float cad0 = fmaxf(cadc[0], 0.f);
  const float cad1 = fmaxf(cadc[1], 0.f);
  const float cad2 = fmaxf(cadc[2], 0.f);
  const float my0 = fmaxf(myoc[0], 0.f);
  const float my1 = fmaxf(myoc[1], 0.f);
  const float my2 = fmaxf(myoc[2], 0.f);
  const float my3 = fmaxf(myoc[3], 0.f);
  const float my4 = fmaxf(myoc[4], 0.f);

  const float m00 = y[i];
  const float m01 = y[i + (size_t)NHW];
  const float m10 = y[i + 2 * (size_t)NHW];
  const float m11 = y[i + 3 * (size_t)NHW];
  const float c = y[i + 4 * (size_t)NHW];
  const float v0 = v[i];
  const float v1 = v[i + (size_t)NHW];
  const float g = gds[i];

  const float dY_m00 = ws[i];
  const float dY_m01 = ws[i + (size_t)NHW];
  const float dY_m10 = ws[i + 2 * (size_t)NHW];
  const float dY_m11 = ws[i + 3 * (size_t)NHW];
  const float dY_c = ws[i + 4 * (size_t)NHW];
  const float dY_v0 = ws[i + 5 * (size_t)NHW];
  const float dY_v1 = ws[i + 6 * (size_t)NHW];
  const float dX_m00 = ws[i + 7 * (size_t)NHW];
  const float dX_m01 = ws[i + 8 * (size_t)NHW];
  const float dX_m10 = ws[i + 9 * (size_t)NHW];
  const float dX_m11 = ws[i + 10 * (size_t)NHW];
  const float dX_c = ws[i + 11 * (size_t)NHW];
  const float dX_v0 = ws[i + 12 * (size_t)NHW];
  const float dX_v1 = ws[i + 13 * (size_t)NHW];

  // gv[i][j] = d_j v_i ; j=0 -> Y, j=1 -> X
  const float gv00 = dY_v0, gv01 = dX_v0, gv10 = dY_v1, gv11 = dX_v1;
  // O = -0.5(gv - gv^T): O01 = ww, O10 = -ww, diag 0
  const float ww = -0.5f * (gv01 - gv10);
  // E = 0.5(gv + gv^T)
  const float E00 = gv00, E11 = gv11;
  const float E01 = 0.5f * (gv01 + gv10);
  const float E10 = E01;

  const float trm = m00 + m11;
  const float dev00 = m00 - 0.5f * trm;
  const float dev01 = m01;
  const float dev10 = m10;
  const float dev11 = m11 - 0.5f * trm;
  const float dmag_sq = dev00 * dev00 + dev01 * dev01 + dev10 * dev10 + dev11 * dev11;
  const float dm = sqrtf(dmag_sq);
  const float dm2 = dm * dm;  // reference squares the sqrt
  const float devE = dev00 * E00 + dev01 * E01 + dev10 * E10 + dev11 * E11;
  const float sg = (devE > 0.f) ? 1.f : ((devE < 0.f) ? -1.f : 0.f);
  const float coef = sg * devE / dm2;
  const float sc = 0.5f * dm / m0;

  const float Ea00 = (E00 - coef * dev00) * sc;
  const float Ea01 = (E01 - coef * dev01) * sc;
  const float Ea10 = (E10 - coef * dev10) * sc;
  const float Ea11 = (E11 - coef * dev11) * sc;
  const float Ep00 = E00 - Ea00;
  const float Ep01 = E01 - Ea01;
  const float Ep10 = E10 - Ea10;
  const float Ep11 = E11 - Ea11;

  // mE = m*Ep + Ep*m
  const float mE00 = (m00 * Ep00 + m01 * Ep10) + (Ep00 * m00 + Ep01 * m10);
  const float mE01 = (m00 * Ep01 + m01 * Ep11) + (Ep00 * m01 + Ep01 * m11);
  const float mE10 = (m10 * Ep00 + m11 * Ep10) + (Ep10 * m00 + Ep11 * m10);
  const float mE11 = (m10 * Ep01 + m11 * Ep11) + (Ep10 * m01 + Ep11 * m11);

  const float divv = gv00 + gv11;
  const float cdot = -(v0 * dY_c + v1 * dX_c) - cad0 * c + cad1 * c * divv + cad2 * g;

  // -(O.m) + (m.O) with O = [[0,ww],[-ww,0]]
  const float md00 = -(v0 * dY_m00 + v1 * dX_m00) - ww * m10 - ww * m01 - my0 * m00 +
                     my1 * mE00 - my2 * c * mE00 + my3 * trm + my4 * trm * m00;
  const float md01 = -(v0 * dY_m01 + v1 * dX_m01) - ww * m11 + ww * m00 - my0 * m01 +
                     my1 * mE01 - my2 * c * mE01 + my4 * trm * m01;
  const float md10 = -(v0 * dY_m10 + v1 * dX_m10) + ww * m00 - ww * m11 - my0 * m10 +
                     my1 * mE10 - my2 * c * mE10 + my4 * trm * m10;
  const float md11 = -(v0 * dY_m11 + v1 * dX_m11) + ww * m01 + ww * m10 - my0 * m11 +
                     my1 * mE11 - my2 * c * mE11 + my4 * trm * m11;

  out[i] = md00;
  out[i + (size_t)NHW] = md01;
  out[i + 2 * (size_t)NHW] = md10;
  out[i + 3 * (size_t)NHW] = md11;
  out[i + 4 * (size_t)NHW] = cdot;
}

extern "C" void kernel_launch(void* const* d_in, const int* in_sizes, int n_in,
                              void* d_out, int out_size, void* d_ws, size_t ws_size,
                              hipStream_t stream) {
  (void)in_sizes; (void)n_in; (void)out_size; (void)ws_size;
  const float* y = (const float*)d_in[0];
  const float* v = (const float*)d_in[1];
  const float* gds = (const float*)d_in[2];
  const float* cadc = (const float*)d_in[3];
  const float* myoc = (const float*)d_in[4];
  float* out = (float*)d_out;

  double* acc = (double*)d_ws;                       // 8B accumulator
  float* kw = (float*)((char*)d_ws + 64);            // 41 weights
  float* planes = (float*)((char*)d_ws + 512);       // 14 x NHW fp32 planes

  hipMemsetAsync(acc, 0, sizeof(double), stream);
  k_weights<<<dim3(1), dim3(64), 0, stream>>>(kw);
  k_reduce<<<dim3(1024), dim3(256), 0, stream>>>(y, acc);
  k_dx<<<dim3(NH, 7), dim3(256), 0, stream>>>(y, v, kw, planes);
  k_dy<<<dim3(NW / 256, NH / 8, 7), dim3(256), 0, stream>>>(y, v, kw, planes);
  k_final<<<dim3(NHW / 256), dim3(256), 0, stream>>>(y, v, gds, cadc, myoc, planes, acc, out);
}

// Round 3
// 327.495 us; speedup vs baseline: 1.1001x; 1.1001x over previous
//
#include <hip/hip_runtime.h>
#include <math.h>

#define RAD 20
#define KLEN 41
#define NH 1024
#define NW 2048
#define NHW (NH * NW)

// ---- Compile-time Gaussian-derivative weights (fp64, matches numpy) ----
// phi = exp(-d^2/50); phi /= sum(phi); k = -d/25 * phi; fold 1/2.27; cast f32.
// exp computed as (exp(-d^2/800))^16 via 30-term Taylor (u<=0.5): ~1e-15 rel.
struct KW { float w[KLEN]; };
constexpr double cexp_neg(double u) {  // exp(-u), 0 <= u <= 0.5
  double term = 1.0, sum = 1.0;
  for (int k = 1; k < 30; ++k) { term *= (-u) / (double)k; sum += term; }
  return sum;
}
constexpr KW make_kw() {
  KW r{};
  double ph[KLEN] = {};
  double s = 0.0;
  for (int i = 0; i < KLEN; ++i) {
    double d = (double)(i - RAD);
    double e = cexp_neg(d * d / 800.0);
    e = e * e; e = e * e; e = e * e; e = e * e;  // ^16
    ph[i] = e; s += e;
  }
  for (int i = 0; i < KLEN; ++i) {
    double d = (double)(i - RAD);
    r.w[i] = (float)((-d / 25.0) * (ph[i] / s) / 2.27);
  }
  return r;
}
static constexpr KW KWC = make_kw();

// m_0 numerator: sum over pixels of ||m||_F (fp32 sqrt, fp64 accumulate).
__global__ __launch_bounds__(256) void k_reduce(const float* __restrict__ y,
                                                double* __restrict__ acc) {
  const int tid = blockIdx.x * blockDim.x + threadIdx.x;
  const int stride = gridDim.x * blockDim.x;
  double local = 0.0;
  for (int i = tid; i < NHW; i += stride) {
    float a = y[i];
    float b = y[i + NHW];
    float c = y[i + 2 * (size_t)NHW];
    float d = y[i + 3 * (size_t)NHW];
    local += (double)sqrtf(a * a + b * b + c * c + d * d);
  }
#pragma unroll
  for (int off = 32; off > 0; off >>= 1) local += __shfl_down(local, off, 64);
  __shared__ double smem[4];
  const int lane = threadIdx.x & 63;
  const int wid = threadIdx.x >> 6;
  if (lane == 0) smem[wid] = local;
  __syncthreads();
  if (threadIdx.x == 0) {
    double s = smem[0] + smem[1] + smem[2] + smem[3];
    atomicAdd(acc, s);
  }
}

// diffX: reflect pad along W, one block = one full row of one channel.
// 256 threads x 8 px/thread = 2048 = NW. Window = 48 floats in registers.
// Weights are inline literals -> K-loop is a pure v_fmac stream.
__global__ __launch_bounds__(256) void k_dx(const float* __restrict__ y,
                                            const float* __restrict__ v,
                                            float* __restrict__ ws) {
  const int t = threadIdx.x;
  const int row = blockIdx.x;
  const int ch = blockIdx.y;  // 0..6 -> y0..y4, v0, v1
  const float* src = (ch < 5) ? (y + (size_t)ch * NHW) : (v + (size_t)(ch - 5) * NHW);
  const float* rp = src + (size_t)row * NW;
  float win[48];
  const int x0 = t * 8 - RAD;  // x0 % 4 == 0 -> float4-aligned when interior
  if (x0 >= 0 && x0 + 48 <= NW) {
#pragma unroll
    for (int i = 0; i < 12; ++i) {
      float4 f = *(const float4*)(rp + x0 + 4 * i);
      win[4 * i + 0] = f.x;
      win[4 * i + 1] = f.y;
      win[4 * i + 2] = f.z;
      win[4 * i + 3] = f.w;
    }
  } else {
#pragma unroll
    for (int i = 0; i < 48; ++i) {
      int xi = x0 + i;
      if (xi < 0) xi = -xi;                  // numpy 'reflect' (no edge repeat)
      if (xi >= NW) xi = 2 * NW - 2 - xi;
      win[i] = rp[xi];
    }
  }
  float res[8];
#pragma unroll
  for (int p = 0; p < 8; ++p) {
    float a = 0.f;
#pragma unroll
    for (int j = 0; j < KLEN; ++j) a = fmaf(win[p + j], KWC.w[j], a);
    res[p] = a;
  }
  float* dst = ws + (size_t)(7 + ch) * NHW + (size_t)row * NW + t * 8;
#pragma unroll
  for (int p = 0; p < 8; ++p) dst[p] = res[p];
}

// diffY: wrap pad along H. Lanes contiguous in x (coalesced row reads),
// each thread produces 8 consecutive rows at its x.
__global__ __launch_bounds__(256) void k_dy(const float* __restrict__ y,
                                            const float* __restrict__ v,
                                            float* __restrict__ ws) {
  const int x = blockIdx.x * 256 + threadIdx.x;
  const int y0 = blockIdx.y * 8;
  const int ch = blockIdx.z;
  const float* src = (ch < 5) ? (y + (size_t)ch * NHW) : (v + (size_t)(ch - 5) * NHW);
  float win[48];
#pragma unroll
  for (int i = 0; i < 48; ++i) {
    int yi = y0 - RAD + i;
    if (yi < 0) yi += NH;     // wrap
    if (yi >= NH) yi -= NH;
    win[i] = src[(size_t)yi * NW + x];
  }
  float* dst = ws + (size_t)ch * NHW + (size_t)y0 * NW + x;
#pragma unroll
  for (int p = 0; p < 8; ++p) {
    float a = 0.f;
#pragma unroll
    for (int j = 0; j < KLEN; ++j) a = fmaf(win[p + j], KWC.w[j], a);
    dst[(size_t)p * NW] = a;
  }
}

// Pointwise 2x2 tensor algebra. ws planes: [0..6]=dY(ch), [7..13]=dX(ch).
__global__ __launch_bounds__(256) void k_final(
    const float* __restrict__ y, const float* __restrict__ v,
    const float* __restrict__ gds, const float* __restrict__ cadc,
    const float* __restrict__ myoc, const float* __restrict__ ws,
    const double* __restrict__ acc, float* __restrict__ out) {
  const size_t i = (size_t)blockIdx.x * blockDim.x + threadIdx.x;
  if (i >= NHW) return;

  const float m0 = (float)(acc[0] / (double)NHW);
  const float cad0 = fmaxf(cadc[0], 0.f);
  const float cad1 = fmaxf(cadc[1], 0.f);
  const float cad2 = fmaxf(cadc[2], 0.f);
  const float my0 = fmaxf(myoc[0], 0.f);
  const float my1 = fmaxf(myoc[1], 0.f);
  const float my2 = fmaxf(myoc[2], 0.f);
  const float my3 = fmaxf(myoc[3], 0.f);
  const float my4 = fmaxf(myoc[4], 0.f);

  const float m00 = y[i];
  const float m01 = y[i + (size_t)NHW];
  const float m10 = y[i + 2 * (size_t)NHW];
  const float m11 = y[i + 3 * (size_t)NHW];
  const float c = y[i + 4 * (size_t)NHW];
  const float v0 = v[i];
  const float v1 = v[i + (size_t)NHW];
  const float g = gds[i];

  const float dY_m00 = ws[i];
  const float dY_m01 = ws[i + (size_t)NHW];
  const float dY_m10 = ws[i + 2 * (size_t)NHW];
  const float dY_m11 = ws[i + 3 * (size_t)NHW];
  const float dY_c = ws[i + 4 * (size_t)NHW];
  const float dY_v0 = ws[i + 5 * (size_t)NHW];
  const float dY_v1 = ws[i + 6 * (size_t)NHW];
  const float dX_m00 = ws[i + 7 * (size_t)NHW];
  const float dX_m01 = ws[i + 8 * (size_t)NHW];
  const float dX_m10 = ws[i + 9 * (size_t)NHW];
  const float dX_m11 = ws[i + 10 * (size_t)NHW];
  const float dX_c = ws[i + 11 * (size_t)NHW];
  const float dX_v0 = ws[i + 12 * (size_t)NHW];
  const float dX_v1 = ws[i + 13 * (size_t)NHW];

  // gv[i][j] = d_j v_i ; j=0 -> Y, j=1 -> X
  const float gv00 = dY_v0, gv01 = dX_v0, gv10 = dY_v1, gv11 = dX_v1;
  // O = -0.5(gv - gv^T): O01 = ww, O10 = -ww, diag 0
  const float ww = -0.5f * (gv01 - gv10);
  // E = 0.5(gv + gv^T)
  const float E00 = gv00, E11 = gv11;
  const float E01 = 0.5f * (gv01 + gv10);
  const float E10 = E01;

  const float trm = m00 + m11;
  const float dev00 = m00 - 0.5f * trm;
  const float dev01 = m01;
  const float dev10 = m10;
  const float dev11 = m11 - 0.5f * trm;
  const float dmag_sq = dev00 * dev00 + dev01 * dev01 + dev10 * dev10 + dev11 * dev11;
  const float dm = sqrtf(dmag_sq);
  const float dm2 = dm * dm;  // reference squares the sqrt
  const float devE = dev00 * E00 + dev01 * E01 + dev10 * E10 + dev11 * E11;
  const float sg = (devE > 0.f) ? 1.f : ((devE < 0.f) ? -1.f : 0.f);
  const float coef = sg * devE / dm2;
  const float sc = 0.5f * dm / m0;

  const float Ea00 = (E00 - coef * dev00) * sc;
  const float Ea01 = (E01 - coef * dev01) * sc;
  const float Ea10 = (E10 - coef * dev10) * sc;
  const float Ea11 = (E11 - coef * dev11) * sc;
  const float Ep00 = E00 - Ea00;
  const float Ep01 = E01 - Ea01;
  const float Ep10 = E10 - Ea10;
  const float Ep11 = E11 - Ea11;

  // mE = m*Ep + Ep*m
  const float mE00 = (m00 * Ep00 + m01 * Ep10) + (Ep00 * m00 + Ep01 * m10);
  const float mE01 = (m00 * Ep01 + m01 * Ep11) + (Ep00 * m01 + Ep01 * m11);
  const float mE10 = (m10 * Ep00 + m11 * Ep10) + (Ep10 * m00 + Ep11 * m10);
  const float mE11 = (m10 * Ep01 + m11 * Ep11) + (Ep10 * m01 + Ep11 * m11);

  const float divv = gv00 + gv11;
  const float cdot = -(v0 * dY_c + v1 * dX_c) - cad0 * c + cad1 * c * divv + cad2 * g;

  // -(O.m) + (m.O) with O = [[0,ww],[-ww,0]]
  const float md00 = -(v0 * dY_m00 + v1 * dX_m00) - ww * m10 - ww * m01 - my0 * m00 +
                     my1 * mE00 - my2 * c * mE00 + my3 * trm + my4 * trm * m00;
  const float md01 = -(v0 * dY_m01 + v1 * dX_m01) - ww * m11 + ww * m00 - my0 * m01 +
                     my1 * mE01 - my2 * c * mE01 + my4 * trm * m01;
  const float md10 = -(v0 * dY_m10 + v1 * dX_m10) + ww * m00 - ww * m11 - my0 * m10 +
                     my1 * mE10 - my2 * c * mE10 + my4 * trm * m10;
  const float md11 = -(v0 * dY_m11 + v1 * dX_m11) + ww * m01 + ww * m10 - my0 * m11 +
                     my1 * mE11 - my2 * c * mE11 + my4 * trm * m11;

  out[i] = md00;
  out[i + (size_t)NHW] = md01;
  out[i + 2 * (size_t)NHW] = md10;
  out[i + 3 * (size_t)NHW] = md11;
  out[i + 4 * (size_t)NHW] = cdot;
}

extern "C" void kernel_launch(void* const* d_in, const int* in_sizes, int n_in,
                              void* d_out, int out_size, void* d_ws, size_t ws_size,
                              hipStream_t stream) {
  (void)in_sizes; (void)n_in; (void)out_size; (void)ws_size;
  const float* y = (const float*)d_in[0];
  const float* v = (const float*)d_in[1];
  const float* gds = (const float*)d_in[2];
  const float* cadc = (const float*)d_in[3];
  const float* myoc = (const float*)d_in[4];
  float* out = (float*)d_out;

  double* acc = (double*)d_ws;                       // 8B accumulator
  float* planes = (float*)((char*)d_ws + 512);       // 14 x NHW fp32 planes

  hipMemsetAsync(acc, 0, sizeof(double), stream);
  k_reduce<<<dim3(1024), dim3(256), 0, stream>>>(y, acc);
  k_dx<<<dim3(NH, 7), dim3(256), 0, stream>>>(y, v, planes);
  k_dy<<<dim3(NW / 256, NH / 8, 7), dim3(256), 0, stream>>>(y, v, planes);
  k_final<<<dim3(NHW / 256), dim3(256), 0, stream>>>(y, v, gds, cadc, myoc, planes, acc, out);
}